// Round 9
// baseline (231.845 us; speedup 1.0000x reference)
//
#include <hip/hip_runtime.h>

#define N_NODES 50000
#define N_EDGES_MAX 800000
#define D_IN    128
#define D_OUT   64

#define BW      64                           // bucket width in nodes (pow2)
#define BSHIFT  6
#define NBKT    ((N_NODES + BW - 1) / BW)    // 782
#define BPAD    1024                         // padded bucket-array size (pow2)
#define PCHUNK  4096                         // edges per partition block
#define HCHUNK  4096                         // edges per hist block
#define ACH     2048                         // edges per aggregate LDS chunk

// ---------------- Phase 1: support = x @ W  (f32 vector FMA) ----------------
#define NPB 16

__global__ __launch_bounds__(256) void gemm_xw(
    const float* __restrict__ x, const float* __restrict__ W,
    float* __restrict__ support) {
  __shared__ float Wlds[D_IN][D_OUT];   // 32 KiB
  __shared__ float xlds[NPB][D_IN];     //  8 KiB
  const int tid = threadIdx.x;
  const int node0 = blockIdx.x * NPB;

  const float4* W4 = (const float4*)W;
  float4* Wl4 = (float4*)Wlds;
#pragma unroll
  for (int i = 0; i < (D_IN * D_OUT / 4) / 256; ++i)
    Wl4[tid + i * 256] = W4[tid + i * 256];

  const float4* x4 = (const float4*)(x + (size_t)node0 * D_IN);
  float4* xl4 = (float4*)xlds;
#pragma unroll
  for (int i = 0; i < (NPB * D_IN / 4) / 256; ++i)
    xl4[tid + i * 256] = x4[tid + i * 256];

  __syncthreads();

  const int f = tid & 63;
  const int g = tid >> 6;
  float acc0 = 0.f, acc1 = 0.f, acc2 = 0.f, acc3 = 0.f;

#pragma unroll
  for (int k = 0; k < D_IN; k += 4) {
    const float w0 = Wlds[k + 0][f];
    const float w1 = Wlds[k + 1][f];
    const float w2 = Wlds[k + 2][f];
    const float w3 = Wlds[k + 3][f];
    const float4 xa = *(const float4*)&xlds[g * 4 + 0][k];
    const float4 xb = *(const float4*)&xlds[g * 4 + 1][k];
    const float4 xc = *(const float4*)&xlds[g * 4 + 2][k];
    const float4 xd = *(const float4*)&xlds[g * 4 + 3][k];
    acc0 += xa.x * w0 + xa.y * w1 + xa.z * w2 + xa.w * w3;
    acc1 += xb.x * w0 + xb.y * w1 + xb.z * w2 + xb.w * w3;
    acc2 += xc.x * w0 + xc.y * w1 + xc.z * w2 + xc.w * w3;
    acc3 += xd.x * w0 + xd.y * w1 + xd.z * w2 + xd.w * w3;
  }

  const int nbase = node0 + g * 4;
  support[(size_t)(nbase + 0) * D_OUT + f] = acc0;
  support[(size_t)(nbase + 1) * D_OUT + f] = acc1;
  support[(size_t)(nbase + 2) * D_OUT + f] = acc2;
  support[(size_t)(nbase + 3) * D_OUT + f] = acc3;
}

// ---------------- Phase 2a: per-bucket histogram (LDS-staged) ---------------
__global__ __launch_bounds__(256) void hist_bucket(
    const int* __restrict__ edst, int* __restrict__ gcnt, int n_edges) {
  __shared__ int lh[BPAD];
  const int t = threadIdx.x;
  for (int b = t; b < BPAD; b += 256) lh[b] = 0;
  __syncthreads();
  const int e0 = blockIdx.x * HCHUNK;
  const int e1 = min(e0 + HCHUNK, n_edges);
  for (int i = e0 + t; i < e1; i += 256)
    atomicAdd(&lh[edst[i] >> BSHIFT], 1);
  __syncthreads();
  for (int b = t; b < BPAD; b += 256) {
    const int c = lh[b];
    if (c) atomicAdd(&gcnt[b], c);
  }
}

// ---------------- Phase 2b: shfl-based scan of 1024 bucket counts -----------
__global__ __launch_bounds__(256) void scan_bucket(
    const int* __restrict__ gcnt, int* __restrict__ goff,
    int* __restrict__ gcur) {
  __shared__ int wsum[4], wpre[4];
  const int t = threadIdx.x, lane = t & 63, w = t >> 6;
  const int4 c = *(const int4*)(gcnt + 4 * t);
  const int s = c.x + c.y + c.z + c.w;
  int incl = s;
#pragma unroll
  for (int off = 1; off < 64; off <<= 1) {
    const int u = __shfl_up(incl, off);
    if (lane >= off) incl += u;
  }
  if (lane == 63) wsum[w] = incl;
  __syncthreads();
  if (t == 0) {
    int run = 0;
#pragma unroll
    for (int i = 0; i < 4; ++i) { wpre[i] = run; run += wsum[i]; }
  }
  __syncthreads();
  const int ex = wpre[w] + incl - s;
  int4 o;
  o.x = ex; o.y = ex + c.x; o.z = ex + c.x + c.y; o.w = ex + c.x + c.y + c.z;
  *(int4*)(goff + 4 * t) = o;
  *(int4*)(gcur + 4 * t) = o;
}

// ---------------- Phase 2c: chunk-sorted bucket partition -------------------
// Register-stage PCHUNK edges, LDS chunk-sort with bucket id PACKED into the
// staged word (src:16 | dstlow:6 | bucket:10), so copy-out needs no binary
// search. Global writes are contiguous per-bucket runs (coalesced).
__global__ __launch_bounds__(512) void partition(
    const int* __restrict__ esrc, const int* __restrict__ edst,
    const float* __restrict__ eval, int* __restrict__ gcur,
    int2* __restrict__ svp, int n_edges) {
  __shared__ int lh[BPAD], lscan[BPAD], lcur[BPAD], lbase[BPAD];
  __shared__ int wsum[8], wpre[8];
  __shared__ int2 stage[PCHUNK];        // 32 KiB (total ~48 KiB)
  const int t = threadIdx.x;
  const int lane = t & 63, w = t >> 6;
  const int e0 = blockIdx.x * PCHUNK;
  const int e1 = min(e0 + PCHUNK, n_edges);

  lh[t] = 0; lh[t + 512] = 0;
  __syncthreads();

  // stage up to 8 edges/thread in registers + local hist
  int  rs[8], rd[8];
  float rv[8];
#pragma unroll
  for (int k = 0; k < 8; ++k) {
    const int i = e0 + t + k * 512;
    if (i < e1) {
      rs[k] = esrc[i]; rd[k] = edst[i]; rv[k] = eval[i];
      atomicAdd(&lh[rd[k] >> BSHIFT], 1);
    } else {
      rs[k] = -1; rd[k] = 0; rv[k] = 0.f;
    }
  }
  __syncthreads();

  // exclusive scan of 1024 counters: thread t owns {2t, 2t+1}; shfl wave-scan
  const int a  = lh[2 * t];
  const int b2 = lh[2 * t + 1];
  const int s = a + b2;
  int incl = s;
#pragma unroll
  for (int off = 1; off < 64; off <<= 1) {
    const int u = __shfl_up(incl, off);
    if (lane >= off) incl += u;
  }
  if (lane == 63) wsum[w] = incl;
  __syncthreads();
  if (t == 0) {
    int run = 0;
#pragma unroll
    for (int i = 0; i < 8; ++i) { wpre[i] = run; run += wsum[i]; }
  }
  __syncthreads();
  const int ex = wpre[w] + incl - s;
  lscan[2 * t]     = ex;
  lscan[2 * t + 1] = ex + a;
  lcur[2 * t]      = ex;
  lcur[2 * t + 1]  = ex + a;
  if (a)  lbase[2 * t]     = atomicAdd(&gcur[2 * t], a);
  if (b2) lbase[2 * t + 1] = atomicAdd(&gcur[2 * t + 1], b2);
  __syncthreads();

  // place packed edges into chunk-sorted LDS staging
#pragma unroll
  for (int k = 0; k < 8; ++k) {
    if (rs[k] >= 0) {
      const int b = rd[k] >> BSHIFT;
      const int r = atomicAdd(&lcur[b], 1);
      stage[r] = make_int2(rs[k] | ((rd[k] & (BW - 1)) << 16) | (b << 22),
                           __float_as_int(rv[k]));
    }
  }
  __syncthreads();

  // copy out in p-order: direct index from packed bucket id (no search);
  // consecutive p within a run -> consecutive global addresses (coalesced)
  const int kn = e1 - e0;
  for (int p = t; p < kn; p += 512) {
    const int2 e = stage[p];
    const int b = (int)((unsigned)e.x >> 22);
    svp[lbase[b] + (p - lscan[b])] = make_int2(e.x & 0x3FFFFF, e.y);
  }
}

// ---------------- Phase 3: per-bucket sort + round-robin register agg -------
// One 256-thread block per 64-node bucket. Counting-sort the bucket's edges
// by dst-low in LDS; each wave owns 16 dst rows and advances all 16 runs in
// lockstep (round-robin) -> up to 16 independent gathers in flight per wave.
__global__ __launch_bounds__(256) void aggregate_bucket(
    const float* __restrict__ support, const int* __restrict__ goff,
    const int2* __restrict__ svp, const float* __restrict__ bias,
    float* __restrict__ out) {
  __shared__ int2 sorted[ACH];          // 16 KiB
  __shared__ int h[BW];
  __shared__ int ro[BW + 1];
  __shared__ int cur[BW];
  const int t = threadIdx.x;
  const int f = t & 63;
  const int wid = t >> 6;               // 0..3 -> rows [wid*16, wid*16+16)
  const int bkt = blockIdx.x;
  const int beg = goff[bkt];
  const int end = goff[bkt + 1];

  float acc[16];
#pragma unroll
  for (int k = 0; k < 16; ++k) acc[k] = 0.f;

  for (int cbeg = beg; cbeg < end; cbeg += ACH) {
    const int cn = min(ACH, end - cbeg);
    if (t < BW) h[t] = 0;
    __syncthreads();

    // stage 8 edges/thread in registers + hist
    int2 m[8];
#pragma unroll
    for (int k = 0; k < 8; ++k) {
      const int i = t + k * 256;
      if (i < cn) {
        m[k] = svp[cbeg + i];
        atomicAdd(&h[(m[k].x >> 16) & 63], 1);
      } else {
        m[k] = make_int2(-1, 0);
      }
    }
    __syncthreads();

    // wave 0: shfl-scan of 64 counters
    if (wid == 0) {
      const int c = h[f];
      int v = c;
#pragma unroll
      for (int off = 1; off < 64; off <<= 1) {
        const int u = __shfl_up(v, off);
        if (f >= off) v += u;
      }
      ro[f] = v - c;
      cur[f] = v - c;
      if (f == 63) ro[64] = cn;
    }
    __syncthreads();

    // place into dst-sorted LDS
#pragma unroll
    for (int k = 0; k < 8; ++k) {
      if (m[k].x >= 0) {
        const int r = atomicAdd(&cur[(m[k].x >> 16) & 63], 1);
        sorted[r] = m[k];
      }
    }
    __syncthreads();

    // round-robin over the wave's 16 rows: 16 independent gather chains
    int idx[16], iend[16];
#pragma unroll
    for (int k = 0; k < 16; ++k) {
      idx[k]  = ro[wid * 16 + k];
      iend[k] = ro[wid * 16 + k + 1];
    }
    bool active = true;
    while (active) {
      active = false;
#pragma unroll
      for (int k = 0; k < 16; ++k) {
        if (idx[k] < iend[k]) {               // wave-uniform branch
          const int2 e = sorted[idx[k]++];    // LDS broadcast
          acc[k] += support[(size_t)(e.x & 0xFFFF) * D_OUT + f] *
                    __int_as_float(e.y);
          active = true;
        }
      }
    }
    __syncthreads();
  }

  const float bf = bias[f];
  const int nbase = bkt * BW;
#pragma unroll
  for (int k = 0; k < 16; ++k) {
    const int node = nbase + wid * 16 + k;
    if (node < N_NODES)
      out[(size_t)node * D_OUT + f] = fmaxf(acc[k] + bf, 0.f);
  }
}

// ---------------- Fallback (ws too small): atomic scatter -------------------
#define EPG 8
__global__ __launch_bounds__(256) void scatter_edges(
    const float* __restrict__ support, const int* __restrict__ esrc,
    const int* __restrict__ edst, const float* __restrict__ eval,
    float* __restrict__ out, int n_edges) {
  const int tid = threadIdx.x;
  const int f = tid & 63;
  const int grp = blockIdx.x * 4 + (tid >> 6);
  const int e0 = grp * EPG;
  int s[EPG], d[EPG];
  float v[EPG];
#pragma unroll
  for (int i = 0; i < EPG; ++i) {
    const int e = e0 + i;
    if (e < n_edges) { s[i] = esrc[e]; d[i] = edst[e]; v[i] = eval[e]; }
    else             { s[i] = 0; d[i] = 0; v[i] = 0.f; }
  }
  float m[EPG];
#pragma unroll
  for (int i = 0; i < EPG; ++i)
    m[i] = support[(size_t)s[i] * D_OUT + f] * v[i];
#pragma unroll
  for (int i = 0; i < EPG; ++i)
    if (e0 + i < n_edges) atomicAdd(&out[(size_t)d[i] * D_OUT + f], m[i]);
}

__global__ __launch_bounds__(256) void bias_relu(
    float* __restrict__ out, const float* __restrict__ b) {
  const int i = blockIdx.x * 256 + threadIdx.x;
  float4* o4 = (float4*)out;
  float4 v = o4[i];
  const int fb = (i * 4) & 63;
  const float4 bb = *(const float4*)&b[fb];
  v.x = fmaxf(v.x + bb.x, 0.f);
  v.y = fmaxf(v.y + bb.y, 0.f);
  v.z = fmaxf(v.z + bb.z, 0.f);
  v.w = fmaxf(v.w + bb.w, 0.f);
  o4[i] = v;
}

extern "C" void kernel_launch(void* const* d_in, const int* in_sizes, int n_in,
                              void* d_out, int out_size, void* d_ws, size_t ws_size,
                              hipStream_t stream) {
  const float* x    = (const float*)d_in[0];
  const int*   esrc = (const int*)  d_in[1];
  const int*   edst = (const int*)  d_in[2];
  const float* eval = (const float*)d_in[3];
  const float* W    = (const float*)d_in[4];
  const float* b    = (const float*)d_in[5];
  float* out = (float*)d_out;
  const int n_edges = in_sizes[1];

  // ---- workspace layout (256B aligned) ----
  size_t off = 0;
  auto alloc = [&](size_t bytes) {
    size_t o = off;
    off = (off + bytes + 255) & ~(size_t)255;
    return o;
  };
  char* ws = (char*)d_ws;
  const size_t sup_o  = alloc((size_t)N_NODES * D_OUT * sizeof(float));
  const size_t cnt_o  = alloc((size_t)BPAD * sizeof(int));
  const size_t offs_o = alloc((size_t)BPAD * sizeof(int));
  const size_t cur_o  = alloc((size_t)BPAD * sizeof(int));
  const size_t svp_o  = alloc((size_t)N_EDGES_MAX * sizeof(int2));
  const size_t req = off;

  float* support = (float*)(ws + sup_o);

  gemm_xw<<<N_NODES / NPB, 256, 0, stream>>>(x, W, support);

  if (ws_size >= req && n_edges <= N_EDGES_MAX) {
    int*  gcnt = (int*) (ws + cnt_o);
    int*  goff = (int*) (ws + offs_o);
    int*  gcur = (int*) (ws + cur_o);
    int2* svp  = (int2*)(ws + svp_o);

    hipMemsetAsync(gcnt, 0, (size_t)BPAD * sizeof(int), stream);

    hist_bucket<<<(n_edges + HCHUNK - 1) / HCHUNK, 256, 0, stream>>>(
        edst, gcnt, n_edges);
    scan_bucket<<<1, 256, 0, stream>>>(gcnt, goff, gcur);
    partition<<<(n_edges + PCHUNK - 1) / PCHUNK, 512, 0, stream>>>(
        esrc, edst, eval, gcur, svp, n_edges);
    aggregate_bucket<<<NBKT, 256, 0, stream>>>(support, goff, svp, b, out);
  } else {
    // fallback: atomic scatter into zeroed out, then bias+relu
    hipMemsetAsync(d_out, 0, (size_t)N_NODES * D_OUT * sizeof(float), stream);
    const int groups = (n_edges + EPG - 1) / EPG;
    scatter_edges<<<(groups + 3) / 4, 256, 0, stream>>>(support, esrc, edst,
                                                        eval, out, n_edges);
    bias_relu<<<N_NODES * D_OUT / 4 / 256, 256, 0, stream>>>(out, b);
  }
}

// Round 10
// 208.713 us; speedup vs baseline: 1.1108x; 1.1108x over previous
//
#include <hip/hip_runtime.h>
#include <hip/hip_fp16.h>

#define N_NODES 50000
#define N_EDGES_MAX 800000
#define D_IN    128
#define D_OUT   64

#define BW      32                           // bucket width in nodes (pow2)
#define BSHIFT  5
#define NBKT    ((N_NODES + BW - 1) / BW)    // 1563
#define BPAD    2048                         // padded bucket-array size (pow2)
#define PCHUNK  2048                         // edges per partition block
#define HCHUNK  4096                         // edges per hist block
#define ACH     2048                         // edges per aggregate LDS chunk

// ---------------- Phase 1: support = x @ W  (f32 FMA, fp16 output) ----------
#define NPB 16

__global__ __launch_bounds__(256) void gemm_xw(
    const float* __restrict__ x, const float* __restrict__ W,
    __half* __restrict__ support) {
  __shared__ float Wlds[D_IN][D_OUT];   // 32 KiB
  __shared__ float xlds[NPB][D_IN];     //  8 KiB
  const int tid = threadIdx.x;
  const int node0 = blockIdx.x * NPB;

  const float4* W4 = (const float4*)W;
  float4* Wl4 = (float4*)Wlds;
#pragma unroll
  for (int i = 0; i < (D_IN * D_OUT / 4) / 256; ++i)
    Wl4[tid + i * 256] = W4[tid + i * 256];

  const float4* x4 = (const float4*)(x + (size_t)node0 * D_IN);
  float4* xl4 = (float4*)xlds;
#pragma unroll
  for (int i = 0; i < (NPB * D_IN / 4) / 256; ++i)
    xl4[tid + i * 256] = x4[tid + i * 256];

  __syncthreads();

  const int f = tid & 63;
  const int g = tid >> 6;
  float acc0 = 0.f, acc1 = 0.f, acc2 = 0.f, acc3 = 0.f;

#pragma unroll
  for (int k = 0; k < D_IN; k += 4) {
    const float w0 = Wlds[k + 0][f];
    const float w1 = Wlds[k + 1][f];
    const float w2 = Wlds[k + 2][f];
    const float w3 = Wlds[k + 3][f];
    const float4 xa = *(const float4*)&xlds[g * 4 + 0][k];
    const float4 xb = *(const float4*)&xlds[g * 4 + 1][k];
    const float4 xc = *(const float4*)&xlds[g * 4 + 2][k];
    const float4 xd = *(const float4*)&xlds[g * 4 + 3][k];
    acc0 += xa.x * w0 + xa.y * w1 + xa.z * w2 + xa.w * w3;
    acc1 += xb.x * w0 + xb.y * w1 + xb.z * w2 + xb.w * w3;
    acc2 += xc.x * w0 + xc.y * w1 + xc.z * w2 + xc.w * w3;
    acc3 += xd.x * w0 + xd.y * w1 + xd.z * w2 + xd.w * w3;
  }

  const int nbase = node0 + g * 4;
  support[(size_t)(nbase + 0) * D_OUT + f] = __float2half(acc0);
  support[(size_t)(nbase + 1) * D_OUT + f] = __float2half(acc1);
  support[(size_t)(nbase + 2) * D_OUT + f] = __float2half(acc2);
  support[(size_t)(nbase + 3) * D_OUT + f] = __float2half(acc3);
}

// ---------------- Phase 2a: per-bucket histogram (LDS-staged) ---------------
__global__ __launch_bounds__(256) void hist_bucket(
    const int* __restrict__ edst, int* __restrict__ gcnt, int n_edges) {
  __shared__ int lh[BPAD];
  const int t = threadIdx.x;
  for (int b = t; b < BPAD; b += 256) lh[b] = 0;
  __syncthreads();
  const int e0 = blockIdx.x * HCHUNK;
  const int e1 = min(e0 + HCHUNK, n_edges);
  for (int i = e0 + t; i < e1; i += 256)
    atomicAdd(&lh[edst[i] >> BSHIFT], 1);
  __syncthreads();
  for (int b = t; b < BPAD; b += 256) {
    const int c = lh[b];
    if (c) atomicAdd(&gcnt[b], c);
  }
}

// ---------------- Phase 2b: shfl-based scan of 2048 bucket counts -----------
__global__ __launch_bounds__(512) void scan_bucket(
    const int* __restrict__ gcnt, int* __restrict__ goff,
    int* __restrict__ gcur) {
  __shared__ int wsum[8], wpre[8];
  const int t = threadIdx.x, lane = t & 63, w = t >> 6;
  const int4 c = *(const int4*)(gcnt + 4 * t);
  const int s = c.x + c.y + c.z + c.w;
  int incl = s;
#pragma unroll
  for (int off = 1; off < 64; off <<= 1) {
    const int u = __shfl_up(incl, off);
    if (lane >= off) incl += u;
  }
  if (lane == 63) wsum[w] = incl;
  __syncthreads();
  if (t == 0) {
    int run = 0;
#pragma unroll
    for (int i = 0; i < 8; ++i) { wpre[i] = run; run += wsum[i]; }
  }
  __syncthreads();
  const int ex = wpre[w] + incl - s;
  int4 o;
  o.x = ex; o.y = ex + c.x; o.z = ex + c.x + c.y; o.w = ex + c.x + c.y + c.z;
  *(int4*)(goff + 4 * t) = o;
  *(int4*)(gcur + 4 * t) = o;
}

// ---------------- Phase 2c: chunk-sorted bucket partition -------------------
// Register-stage PCHUNK edges, LDS chunk-sort with bucket id PACKED into the
// staged word (src:16 | dstlow:5 | bucket:11) -> copy-out needs no search.
__global__ __launch_bounds__(512) void partition(
    const int* __restrict__ esrc, const int* __restrict__ edst,
    const float* __restrict__ eval, int* __restrict__ gcur,
    int2* __restrict__ svp, int n_edges) {
  __shared__ int lh[BPAD], lscan[BPAD], lcur[BPAD], lbase[BPAD];  // 32 KiB
  __shared__ int wsum[8], wpre[8];
  __shared__ int2 stage[PCHUNK];        // 16 KiB
  const int t = threadIdx.x;
  const int lane = t & 63, w = t >> 6;
  const int e0 = blockIdx.x * PCHUNK;
  const int e1 = min(e0 + PCHUNK, n_edges);

  lh[t] = 0; lh[t + 512] = 0; lh[t + 1024] = 0; lh[t + 1536] = 0;
  __syncthreads();

  // stage up to 4 edges/thread in registers + local hist
  int  rs[4], rd[4];
  float rv[4];
#pragma unroll
  for (int k = 0; k < 4; ++k) {
    const int i = e0 + t + k * 512;
    if (i < e1) {
      rs[k] = esrc[i]; rd[k] = edst[i]; rv[k] = eval[i];
      atomicAdd(&lh[rd[k] >> BSHIFT], 1);
    } else {
      rs[k] = -1; rd[k] = 0; rv[k] = 0.f;
    }
  }
  __syncthreads();

  // exclusive scan of 2048 counters: thread t owns {4t..4t+3}; shfl wave-scan
  const int a0 = lh[4 * t], a1 = lh[4 * t + 1];
  const int a2 = lh[4 * t + 2], a3 = lh[4 * t + 3];
  const int s = a0 + a1 + a2 + a3;
  int incl = s;
#pragma unroll
  for (int off = 1; off < 64; off <<= 1) {
    const int u = __shfl_up(incl, off);
    if (lane >= off) incl += u;
  }
  if (lane == 63) wsum[w] = incl;
  __syncthreads();
  if (t == 0) {
    int run = 0;
#pragma unroll
    for (int i = 0; i < 8; ++i) { wpre[i] = run; run += wsum[i]; }
  }
  __syncthreads();
  const int ex = wpre[w] + incl - s;
  lscan[4 * t]     = ex;
  lscan[4 * t + 1] = ex + a0;
  lscan[4 * t + 2] = ex + a0 + a1;
  lscan[4 * t + 3] = ex + a0 + a1 + a2;
  lcur[4 * t]      = ex;
  lcur[4 * t + 1]  = ex + a0;
  lcur[4 * t + 2]  = ex + a0 + a1;
  lcur[4 * t + 3]  = ex + a0 + a1 + a2;
  if (a0) lbase[4 * t]     = atomicAdd(&gcur[4 * t],     a0);
  if (a1) lbase[4 * t + 1] = atomicAdd(&gcur[4 * t + 1], a1);
  if (a2) lbase[4 * t + 2] = atomicAdd(&gcur[4 * t + 2], a2);
  if (a3) lbase[4 * t + 3] = atomicAdd(&gcur[4 * t + 3], a3);
  __syncthreads();

  // place packed edges into chunk-sorted LDS staging
#pragma unroll
  for (int k = 0; k < 4; ++k) {
    if (rs[k] >= 0) {
      const int b = rd[k] >> BSHIFT;
      const int r = atomicAdd(&lcur[b], 1);
      stage[r] = make_int2(rs[k] | ((rd[k] & (BW - 1)) << 16) | (b << 21),
                           __float_as_int(rv[k]));
    }
  }
  __syncthreads();

  // copy out: direct index from packed bucket id; coalesced per-run writes
  const int kn = e1 - e0;
  for (int p = t; p < kn; p += 512) {
    const int2 e = stage[p];
    const int b = (int)((unsigned)e.x >> 21);
    svp[lbase[b] + (p - lscan[b])] = make_int2(e.x & 0x1FFFFF, e.y);
  }
}

// ---------------- Phase 3: per-bucket sort + register aggregation -----------
// One 256-thread block per 32-node bucket (1563 blocks -> fine-grained
// balance). Counting-sort by dst-low in LDS; each wave owns 8 rows,
// sequential per-row runs (loads within a run are independent -> ILP),
// accumulate in registers, one fused bias+relu write per output row.
__global__ __launch_bounds__(256) void aggregate_bucket(
    const __half* __restrict__ support, const int* __restrict__ goff,
    const int2* __restrict__ svp, const float* __restrict__ bias,
    float* __restrict__ out) {
  __shared__ int2 sorted[ACH];          // 16 KiB
  __shared__ int h[BW];
  __shared__ int ro[BW + 1];
  __shared__ int cur[BW];
  const int t = threadIdx.x;
  const int f = t & 63;
  const int wid = t >> 6;               // 0..3 -> rows [wid*8, wid*8+8)
  const int bkt = blockIdx.x;
  const int beg = goff[bkt];
  const int end = goff[bkt + 1];

  float acc[8];
#pragma unroll
  for (int k = 0; k < 8; ++k) acc[k] = 0.f;

  for (int cbeg = beg; cbeg < end; cbeg += ACH) {
    const int cn = min(ACH, end - cbeg);
    if (t < BW) h[t] = 0;
    __syncthreads();

    // stage 8 edges/thread in registers + hist
    int2 m[8];
#pragma unroll
    for (int k = 0; k < 8; ++k) {
      const int i = t + k * 256;
      if (i < cn) {
        m[k] = svp[cbeg + i];
        atomicAdd(&h[(m[k].x >> 16) & (BW - 1)], 1);
      } else {
        m[k] = make_int2(-1, 0);
      }
    }
    __syncthreads();

    // wave 0: shfl-scan of 32 counters (lanes 0..31 carry the data)
    if (wid == 0) {
      const int c = (f < BW) ? h[f] : 0;
      int v = c;
#pragma unroll
      for (int off = 1; off < 64; off <<= 1) {
        const int u = __shfl_up(v, off);
        if (f >= off) v += u;
      }
      if (f < BW) { ro[f] = v - c; cur[f] = v - c; }
      if (f == BW - 1) ro[BW] = cn;
    }
    __syncthreads();

    // place into dst-sorted LDS
#pragma unroll
    for (int k = 0; k < 8; ++k) {
      if (m[k].x >= 0) {
        const int r = atomicAdd(&cur[(m[k].x >> 16) & (BW - 1)], 1);
        sorted[r] = m[k];
      }
    }
    __syncthreads();

    // sequential per-row runs; loads within a run are independent
#pragma unroll
    for (int k = 0; k < 8; ++k) {
      const int row = wid * 8 + k;
      const int rb = ro[row];
      const int re = ro[row + 1];
      for (int j = rb; j < re; ++j) {
        const int2 e = sorted[j];                  // wave-uniform broadcast
        acc[k] += __half2float(support[(size_t)(e.x & 0xFFFF) * D_OUT + f]) *
                  __int_as_float(e.y);
      }
    }
    __syncthreads();
  }

  const float bf = bias[f];
  const int nbase = bkt * BW;
#pragma unroll
  for (int k = 0; k < 8; ++k) {
    const int node = nbase + wid * 8 + k;
    if (node < N_NODES)
      out[(size_t)node * D_OUT + f] = fmaxf(acc[k] + bf, 0.f);
  }
}

// ---------------- Fallback (ws too small): atomic scatter -------------------
#define EPG 8
__global__ __launch_bounds__(256) void scatter_edges(
    const __half* __restrict__ support, const int* __restrict__ esrc,
    const int* __restrict__ edst, const float* __restrict__ eval,
    float* __restrict__ out, int n_edges) {
  const int tid = threadIdx.x;
  const int f = tid & 63;
  const int grp = blockIdx.x * 4 + (tid >> 6);
  const int e0 = grp * EPG;
  int s[EPG], d[EPG];
  float v[EPG];
#pragma unroll
  for (int i = 0; i < EPG; ++i) {
    const int e = e0 + i;
    if (e < n_edges) { s[i] = esrc[e]; d[i] = edst[e]; v[i] = eval[e]; }
    else             { s[i] = 0; d[i] = 0; v[i] = 0.f; }
  }
  float m[EPG];
#pragma unroll
  for (int i = 0; i < EPG; ++i)
    m[i] = __half2float(support[(size_t)s[i] * D_OUT + f]) * v[i];
#pragma unroll
  for (int i = 0; i < EPG; ++i)
    if (e0 + i < n_edges) atomicAdd(&out[(size_t)d[i] * D_OUT + f], m[i]);
}

__global__ __launch_bounds__(256) void bias_relu(
    float* __restrict__ out, const float* __restrict__ b) {
  const int i = blockIdx.x * 256 + threadIdx.x;
  float4* o4 = (float4*)out;
  float4 v = o4[i];
  const int fb = (i * 4) & 63;
  const float4 bb = *(const float4*)&b[fb];
  v.x = fmaxf(v.x + bb.x, 0.f);
  v.y = fmaxf(v.y + bb.y, 0.f);
  v.z = fmaxf(v.z + bb.z, 0.f);
  v.w = fmaxf(v.w + bb.w, 0.f);
  o4[i] = v;
}

extern "C" void kernel_launch(void* const* d_in, const int* in_sizes, int n_in,
                              void* d_out, int out_size, void* d_ws, size_t ws_size,
                              hipStream_t stream) {
  const float* x    = (const float*)d_in[0];
  const int*   esrc = (const int*)  d_in[1];
  const int*   edst = (const int*)  d_in[2];
  const float* eval = (const float*)d_in[3];
  const float* W    = (const float*)d_in[4];
  const float* b    = (const float*)d_in[5];
  float* out = (float*)d_out;
  const int n_edges = in_sizes[1];

  // ---- workspace layout (256B aligned) ----
  size_t off = 0;
  auto alloc = [&](size_t bytes) {
    size_t o = off;
    off = (off + bytes + 255) & ~(size_t)255;
    return o;
  };
  char* ws = (char*)d_ws;
  const size_t sup_o  = alloc((size_t)N_NODES * D_OUT * sizeof(__half));
  const size_t cnt_o  = alloc((size_t)BPAD * sizeof(int));
  const size_t offs_o = alloc((size_t)BPAD * sizeof(int));
  const size_t cur_o  = alloc((size_t)BPAD * sizeof(int));
  const size_t svp_o  = alloc((size_t)N_EDGES_MAX * sizeof(int2));
  const size_t req = off;

  __half* support = (__half*)(ws + sup_o);

  gemm_xw<<<N_NODES / NPB, 256, 0, stream>>>(x, W, support);

  if (ws_size >= req && n_edges <= N_EDGES_MAX) {
    int*  gcnt = (int*) (ws + cnt_o);
    int*  goff = (int*) (ws + offs_o);
    int*  gcur = (int*) (ws + cur_o);
    int2* svp  = (int2*)(ws + svp_o);

    hipMemsetAsync(gcnt, 0, (size_t)BPAD * sizeof(int), stream);

    hist_bucket<<<(n_edges + HCHUNK - 1) / HCHUNK, 256, 0, stream>>>(
        edst, gcnt, n_edges);
    scan_bucket<<<1, 512, 0, stream>>>(gcnt, goff, gcur);
    partition<<<(n_edges + PCHUNK - 1) / PCHUNK, 512, 0, stream>>>(
        esrc, edst, eval, gcur, svp, n_edges);
    aggregate_bucket<<<NBKT, 256, 0, stream>>>(support, goff, svp, b, out);
  } else {
    // fallback: atomic scatter into zeroed out, then bias+relu
    hipMemsetAsync(d_out, 0, (size_t)N_NODES * D_OUT * sizeof(float), stream);
    const int groups = (n_edges + EPG - 1) / EPG;
    scatter_edges<<<(groups + 3) / 4, 256, 0, stream>>>(support, esrc, edst,
                                                        eval, out, n_edges);
    bias_relu<<<N_NODES * D_OUT / 4 / 256, 256, 0, stream>>>(out, b);
  }
}

// Round 11
// 179.647 us; speedup vs baseline: 1.2906x; 1.1618x over previous
//
#include <hip/hip_runtime.h>
#include <hip/hip_fp16.h>

#define N_NODES 50000
#define N_EDGES_MAX 800000
#define D_IN    128
#define D_OUT   64

#define BW      32                           // bucket width in nodes (pow2)
#define BSHIFT  5
#define NBKT    ((N_NODES + BW - 1) / BW)    // 1563
#define BPAD    2048                         // padded bucket-array size (pow2)
#define PCHUNK  2048                         // edges per partition block
#define HCHUNK  2048                         // edges per hist block
#define ACH     2048                         // edges per aggregate LDS chunk

// ---------------- Phase 1: support = x @ W  (f32 FMA, fp16 output) ----------
#define NPB 16

__global__ __launch_bounds__(256) void gemm_xw(
    const float* __restrict__ x, const float* __restrict__ W,
    __half* __restrict__ support) {
  __shared__ float Wlds[D_IN][D_OUT];   // 32 KiB
  __shared__ float xlds[NPB][D_IN];     //  8 KiB
  const int tid = threadIdx.x;
  const int node0 = blockIdx.x * NPB;

  const float4* W4 = (const float4*)W;
  float4* Wl4 = (float4*)Wlds;
#pragma unroll
  for (int i = 0; i < (D_IN * D_OUT / 4) / 256; ++i)
    Wl4[tid + i * 256] = W4[tid + i * 256];

  const float4* x4 = (const float4*)(x + (size_t)node0 * D_IN);
  float4* xl4 = (float4*)xlds;
#pragma unroll
  for (int i = 0; i < (NPB * D_IN / 4) / 256; ++i)
    xl4[tid + i * 256] = x4[tid + i * 256];

  __syncthreads();

  const int f = tid & 63;
  const int g = tid >> 6;
  float acc0 = 0.f, acc1 = 0.f, acc2 = 0.f, acc3 = 0.f;

#pragma unroll
  for (int k = 0; k < D_IN; k += 4) {
    const float w0 = Wlds[k + 0][f];
    const float w1 = Wlds[k + 1][f];
    const float w2 = Wlds[k + 2][f];
    const float w3 = Wlds[k + 3][f];
    const float4 xa = *(const float4*)&xlds[g * 4 + 0][k];
    const float4 xb = *(const float4*)&xlds[g * 4 + 1][k];
    const float4 xc = *(const float4*)&xlds[g * 4 + 2][k];
    const float4 xd = *(const float4*)&xlds[g * 4 + 3][k];
    acc0 += xa.x * w0 + xa.y * w1 + xa.z * w2 + xa.w * w3;
    acc1 += xb.x * w0 + xb.y * w1 + xb.z * w2 + xb.w * w3;
    acc2 += xc.x * w0 + xc.y * w1 + xc.z * w2 + xc.w * w3;
    acc3 += xd.x * w0 + xd.y * w1 + xd.z * w2 + xd.w * w3;
  }

  const int nbase = node0 + g * 4;
  support[(size_t)(nbase + 0) * D_OUT + f] = __float2half(acc0);
  support[(size_t)(nbase + 1) * D_OUT + f] = __float2half(acc1);
  support[(size_t)(nbase + 2) * D_OUT + f] = __float2half(acc2);
  support[(size_t)(nbase + 3) * D_OUT + f] = __float2half(acc3);
}

// ---------------- Phase 2a: per-bucket histogram (LDS-staged) ---------------
__global__ __launch_bounds__(256) void hist_bucket(
    const int* __restrict__ edst, int* __restrict__ gcnt, int n_edges) {
  __shared__ int lh[BPAD];
  const int t = threadIdx.x;
  for (int b = t; b < BPAD; b += 256) lh[b] = 0;
  __syncthreads();
  const int e0 = blockIdx.x * HCHUNK;
  const int e1 = min(e0 + HCHUNK, n_edges);
  for (int i = e0 + t; i < e1; i += 256)
    atomicAdd(&lh[edst[i] >> BSHIFT], 1);
  __syncthreads();
  for (int b = t; b < BPAD; b += 256) {
    const int c = lh[b];
    if (c) atomicAdd(&gcnt[b], c);
  }
}

// ---------------- Phase 2b: shfl-based scan of 2048 bucket counts -----------
__global__ __launch_bounds__(512) void scan_bucket(
    const int* __restrict__ gcnt, int* __restrict__ goff,
    int* __restrict__ gcur) {
  __shared__ int wsum[8], wpre[8];
  const int t = threadIdx.x, lane = t & 63, w = t >> 6;
  const int4 c = *(const int4*)(gcnt + 4 * t);
  const int s = c.x + c.y + c.z + c.w;
  int incl = s;
#pragma unroll
  for (int off = 1; off < 64; off <<= 1) {
    const int u = __shfl_up(incl, off);
    if (lane >= off) incl += u;
  }
  if (lane == 63) wsum[w] = incl;
  __syncthreads();
  if (t == 0) {
    int run = 0;
#pragma unroll
    for (int i = 0; i < 8; ++i) { wpre[i] = run; run += wsum[i]; }
  }
  __syncthreads();
  const int ex = wpre[w] + incl - s;
  int4 o;
  o.x = ex; o.y = ex + c.x; o.z = ex + c.x + c.y; o.w = ex + c.x + c.y + c.z;
  *(int4*)(goff + 4 * t) = o;
  *(int4*)(gcur + 4 * t) = o;
}

// ---------------- Phase 2c: chunk-sorted bucket partition -------------------
// Register-stage PCHUNK edges, LDS chunk-sort with bucket id PACKED into the
// staged word (src:16 | dstlow:5 | bucket:11) -> copy-out needs no search.
__global__ __launch_bounds__(512) void partition(
    const int* __restrict__ esrc, const int* __restrict__ edst,
    const float* __restrict__ eval, int* __restrict__ gcur,
    int2* __restrict__ svp, int n_edges) {
  __shared__ int lh[BPAD], lscan[BPAD], lcur[BPAD], lbase[BPAD];  // 32 KiB
  __shared__ int wsum[8], wpre[8];
  __shared__ int2 stage[PCHUNK];        // 16 KiB
  const int t = threadIdx.x;
  const int lane = t & 63, w = t >> 6;
  const int e0 = blockIdx.x * PCHUNK;
  const int e1 = min(e0 + PCHUNK, n_edges);

  lh[t] = 0; lh[t + 512] = 0; lh[t + 1024] = 0; lh[t + 1536] = 0;
  __syncthreads();

  // stage up to 4 edges/thread in registers + local hist
  int  rs[4], rd[4];
  float rv[4];
#pragma unroll
  for (int k = 0; k < 4; ++k) {
    const int i = e0 + t + k * 512;
    if (i < e1) {
      rs[k] = esrc[i]; rd[k] = edst[i]; rv[k] = eval[i];
      atomicAdd(&lh[rd[k] >> BSHIFT], 1);
    } else {
      rs[k] = -1; rd[k] = 0; rv[k] = 0.f;
    }
  }
  __syncthreads();

  // exclusive scan of 2048 counters: thread t owns {4t..4t+3}; shfl wave-scan
  const int a0 = lh[4 * t], a1 = lh[4 * t + 1];
  const int a2 = lh[4 * t + 2], a3 = lh[4 * t + 3];
  const int s = a0 + a1 + a2 + a3;
  int incl = s;
#pragma unroll
  for (int off = 1; off < 64; off <<= 1) {
    const int u = __shfl_up(incl, off);
    if (lane >= off) incl += u;
  }
  if (lane == 63) wsum[w] = incl;
  __syncthreads();
  if (t == 0) {
    int run = 0;
#pragma unroll
    for (int i = 0; i < 8; ++i) { wpre[i] = run; run += wsum[i]; }
  }
  __syncthreads();
  const int ex = wpre[w] + incl - s;
  lscan[4 * t]     = ex;
  lscan[4 * t + 1] = ex + a0;
  lscan[4 * t + 2] = ex + a0 + a1;
  lscan[4 * t + 3] = ex + a0 + a1 + a2;
  lcur[4 * t]      = ex;
  lcur[4 * t + 1]  = ex + a0;
  lcur[4 * t + 2]  = ex + a0 + a1;
  lcur[4 * t + 3]  = ex + a0 + a1 + a2;
  if (a0) lbase[4 * t]     = atomicAdd(&gcur[4 * t],     a0);
  if (a1) lbase[4 * t + 1] = atomicAdd(&gcur[4 * t + 1], a1);
  if (a2) lbase[4 * t + 2] = atomicAdd(&gcur[4 * t + 2], a2);
  if (a3) lbase[4 * t + 3] = atomicAdd(&gcur[4 * t + 3], a3);
  __syncthreads();

  // place packed edges into chunk-sorted LDS staging
#pragma unroll
  for (int k = 0; k < 4; ++k) {
    if (rs[k] >= 0) {
      const int b = rd[k] >> BSHIFT;
      const int r = atomicAdd(&lcur[b], 1);
      stage[r] = make_int2(rs[k] | ((rd[k] & (BW - 1)) << 16) | (b << 21),
                           __float_as_int(rv[k]));
    }
  }
  __syncthreads();

  // copy out: direct index from packed bucket id; coalesced per-run writes.
  // Full chunks take a batched path (4 independent read->write chains).
  const int kn = e1 - e0;
  if (kn == PCHUNK) {
    const int2 E0 = stage[t];
    const int2 E1 = stage[t + 512];
    const int2 E2 = stage[t + 1024];
    const int2 E3 = stage[t + 1536];
    const int b0 = (int)((unsigned)E0.x >> 21);
    const int b1 = (int)((unsigned)E1.x >> 21);
    const int b2i = (int)((unsigned)E2.x >> 21);
    const int b3 = (int)((unsigned)E3.x >> 21);
    svp[lbase[b0] + (t         - lscan[b0])] = make_int2(E0.x & 0x1FFFFF, E0.y);
    svp[lbase[b1] + (t + 512  - lscan[b1])] = make_int2(E1.x & 0x1FFFFF, E1.y);
    svp[lbase[b2i] + (t + 1024 - lscan[b2i])] = make_int2(E2.x & 0x1FFFFF, E2.y);
    svp[lbase[b3] + (t + 1536 - lscan[b3])] = make_int2(E3.x & 0x1FFFFF, E3.y);
  } else {
    for (int p = t; p < kn; p += 512) {
      const int2 e = stage[p];
      const int b = (int)((unsigned)e.x >> 21);
      svp[lbase[b] + (p - lscan[b])] = make_int2(e.x & 0x1FFFFF, e.y);
    }
  }
}

// ---------------- Phase 3: per-bucket sort + batched register agg -----------
// One 256-thread block per 32-node bucket. Counting-sort by dst-low in LDS;
// each wave owns 8 rows. Gather loop is software-pipelined in batches of 8:
// 8 independent ds_reads -> 8 independent global gathers -> 8 FMAs, so the
// per-edge latency chain (~350cy) is amortized 8x.
__global__ __launch_bounds__(256) void aggregate_bucket(
    const __half* __restrict__ support, const int* __restrict__ goff,
    const int2* __restrict__ svp, const float* __restrict__ bias,
    float* __restrict__ out) {
  __shared__ int2 sorted[ACH];          // 16 KiB
  __shared__ int h[BW];
  __shared__ int ro[BW + 1];
  __shared__ int cur[BW];
  const int t = threadIdx.x;
  const int f = t & 63;
  const int wid = t >> 6;               // 0..3 -> rows [wid*8, wid*8+8)
  const int bkt = blockIdx.x;
  const int beg = goff[bkt];
  const int end = goff[bkt + 1];

  float acc[8];
#pragma unroll
  for (int k = 0; k < 8; ++k) acc[k] = 0.f;

  for (int cbeg = beg; cbeg < end; cbeg += ACH) {
    const int cn = min(ACH, end - cbeg);
    if (t < BW) h[t] = 0;
    __syncthreads();

    // stage 8 edges/thread in registers + hist
    int2 m[8];
#pragma unroll
    for (int k = 0; k < 8; ++k) {
      const int i = t + k * 256;
      if (i < cn) {
        m[k] = svp[cbeg + i];
        atomicAdd(&h[(m[k].x >> 16) & (BW - 1)], 1);
      } else {
        m[k] = make_int2(-1, 0);
      }
    }
    __syncthreads();

    // wave 0: shfl-scan of 32 counters (lanes 0..31 carry the data)
    if (wid == 0) {
      const int c = (f < BW) ? h[f] : 0;
      int v = c;
#pragma unroll
      for (int off = 1; off < 64; off <<= 1) {
        const int u = __shfl_up(v, off);
        if (f >= off) v += u;
      }
      if (f < BW) { ro[f] = v - c; cur[f] = v - c; }
      if (f == BW - 1) ro[BW] = cn;
    }
    __syncthreads();

    // place into dst-sorted LDS
#pragma unroll
    for (int k = 0; k < 8; ++k) {
      if (m[k].x >= 0) {
        const int r = atomicAdd(&cur[(m[k].x >> 16) & (BW - 1)], 1);
        sorted[r] = m[k];
      }
    }
    __syncthreads();

    // batched per-row runs: batch-8 pipeline + serial tail
#pragma unroll
    for (int k = 0; k < 8; ++k) {
      const int row = wid * 8 + k;
      int j = ro[row];
      const int re = ro[row + 1];
      for (; j + 8 <= re; j += 8) {
        int2 e[8];
#pragma unroll
        for (int u = 0; u < 8; ++u) e[u] = sorted[j + u];
        float s[8];
#pragma unroll
        for (int u = 0; u < 8; ++u)
          s[u] = __half2float(support[(size_t)(e[u].x & 0xFFFF) * D_OUT + f]);
#pragma unroll
        for (int u = 0; u < 8; ++u)
          acc[k] = fmaf(s[u], __int_as_float(e[u].y), acc[k]);
      }
      for (; j < re; ++j) {
        const int2 e = sorted[j];
        acc[k] = fmaf(__half2float(support[(size_t)(e.x & 0xFFFF) * D_OUT + f]),
                      __int_as_float(e.y), acc[k]);
      }
    }
    __syncthreads();
  }

  const float bf = bias[f];
  const int nbase = bkt * BW;
#pragma unroll
  for (int k = 0; k < 8; ++k) {
    const int node = nbase + wid * 8 + k;
    if (node < N_NODES)
      out[(size_t)node * D_OUT + f] = fmaxf(acc[k] + bf, 0.f);
  }
}

// ---------------- Fallback (ws too small): atomic scatter -------------------
#define EPG 8
__global__ __launch_bounds__(256) void scatter_edges(
    const __half* __restrict__ support, const int* __restrict__ esrc,
    const int* __restrict__ edst, const float* __restrict__ eval,
    float* __restrict__ out, int n_edges) {
  const int tid = threadIdx.x;
  const int f = tid & 63;
  const int grp = blockIdx.x * 4 + (tid >> 6);
  const int e0 = grp * EPG;
  int s[EPG], d[EPG];
  float v[EPG];
#pragma unroll
  for (int i = 0; i < EPG; ++i) {
    const int e = e0 + i;
    if (e < n_edges) { s[i] = esrc[e]; d[i] = edst[e]; v[i] = eval[e]; }
    else             { s[i] = 0; d[i] = 0; v[i] = 0.f; }
  }
  float m[EPG];
#pragma unroll
  for (int i = 0; i < EPG; ++i)
    m[i] = __half2float(support[(size_t)s[i] * D_OUT + f]) * v[i];
#pragma unroll
  for (int i = 0; i < EPG; ++i)
    if (e0 + i < n_edges) atomicAdd(&out[(size_t)d[i] * D_OUT + f], m[i]);
}

__global__ __launch_bounds__(256) void bias_relu(
    float* __restrict__ out, const float* __restrict__ b) {
  const int i = blockIdx.x * 256 + threadIdx.x;
  float4* o4 = (float4*)out;
  float4 v = o4[i];
  const int fb = (i * 4) & 63;
  const float4 bb = *(const float4*)&b[fb];
  v.x = fmaxf(v.x + bb.x, 0.f);
  v.y = fmaxf(v.y + bb.y, 0.f);
  v.z = fmaxf(v.z + bb.z, 0.f);
  v.w = fmaxf(v.w + bb.w, 0.f);
  o4[i] = v;
}

extern "C" void kernel_launch(void* const* d_in, const int* in_sizes, int n_in,
                              void* d_out, int out_size, void* d_ws, size_t ws_size,
                              hipStream_t stream) {
  const float* x    = (const float*)d_in[0];
  const int*   esrc = (const int*)  d_in[1];
  const int*   edst = (const int*)  d_in[2];
  const float* eval = (const float*)d_in[3];
  const float* W    = (const float*)d_in[4];
  const float* b    = (const float*)d_in[5];
  float* out = (float*)d_out;
  const int n_edges = in_sizes[1];

  // ---- workspace layout (256B aligned) ----
  size_t off = 0;
  auto alloc = [&](size_t bytes) {
    size_t o = off;
    off = (off + bytes + 255) & ~(size_t)255;
    return o;
  };
  char* ws = (char*)d_ws;
  const size_t sup_o  = alloc((size_t)N_NODES * D_OUT * sizeof(__half));
  const size_t cnt_o  = alloc((size_t)BPAD * sizeof(int));
  const size_t offs_o = alloc((size_t)BPAD * sizeof(int));
  const size_t cur_o  = alloc((size_t)BPAD * sizeof(int));
  const size_t svp_o  = alloc((size_t)N_EDGES_MAX * sizeof(int2));
  const size_t req = off;

  __half* support = (__half*)(ws + sup_o);

  gemm_xw<<<N_NODES / NPB, 256, 0, stream>>>(x, W, support);

  if (ws_size >= req && n_edges <= N_EDGES_MAX) {
    int*  gcnt = (int*) (ws + cnt_o);
    int*  goff = (int*) (ws + offs_o);
    int*  gcur = (int*) (ws + cur_o);
    int2* svp  = (int2*)(ws + svp_o);

    hipMemsetAsync(gcnt, 0, (size_t)BPAD * sizeof(int), stream);

    hist_bucket<<<(n_edges + HCHUNK - 1) / HCHUNK, 256, 0, stream>>>(
        edst, gcnt, n_edges);
    scan_bucket<<<1, 512, 0, stream>>>(gcnt, goff, gcur);
    partition<<<(n_edges + PCHUNK - 1) / PCHUNK, 512, 0, stream>>>(
        esrc, edst, eval, gcur, svp, n_edges);
    aggregate_bucket<<<NBKT, 256, 0, stream>>>(support, goff, svp, b, out);
  } else {
    // fallback: atomic scatter into zeroed out, then bias+relu
    hipMemsetAsync(d_out, 0, (size_t)N_NODES * D_OUT * sizeof(float), stream);
    const int groups = (n_edges + EPG - 1) / EPG;
    scatter_edges<<<(groups + 3) / 4, 256, 0, stream>>>(support, esrc, edst,
                                                        eval, out, n_edges);
    bias_relu<<<N_NODES * D_OUT / 4 / 256, 256, 0, stream>>>(out, b);
  }
}